// Round 13
// baseline (126.327 us; speedup 1.0000x reference)
//
#include <hip/hip_runtime.h>
#include <hip/hip_bf16.h>

typedef __bf16 bf16_t;
typedef __bf16 bf16x8 __attribute__((ext_vector_type(8)));
typedef float f32x4 __attribute__((ext_vector_type(4)));
typedef float f32x16 __attribute__((ext_vector_type(16)));
typedef unsigned int u32x2 __attribute__((ext_vector_type(2)));
typedef unsigned int u32x4 __attribute__((ext_vector_type(4)));

#define MFMA16(A,B,C) __builtin_amdgcn_mfma_f32_16x16x32_bf16(A,B,C,0,0,0)
#define MFMA32(A,B,C) __builtin_amdgcn_mfma_f32_32x32x16_bf16(A,B,C,0,0,0)

// exp(s/8) computed as exp2(s * 0.125*log2(e)); the scale is folded into Q.
#define QSCALE 0.18033688011112042f

__device__ inline unsigned pk_bf16(float lo, float hi) {
  unsigned r;
  asm("v_cvt_pk_bf16_f32 %0, %1, %2" : "=v"(r) : "v"(lo), "v"(hi));
  return r;
}
__device__ inline bf16x8 frag4(unsigned a, unsigned b, unsigned c, unsigned d) {
  union { u32x4 u; bf16x8 f; } x;
  x.u = (u32x4){a, b, c, d};
  return x.f;
}
__device__ inline void gload16(const bf16_t* g, const bf16_t* l) {
  __builtin_amdgcn_global_load_lds(
      (const __attribute__((address_space(1))) unsigned int*)g,
      (__attribute__((address_space(3))) unsigned int*)l, 16, 0, 0);
}

// ---------------------------------------------------------------------------
// Kernel 0: one-time w_in fp32 -> bf16 conversion (192*512 = 98304 elems).
// ---------------------------------------------------------------------------
__global__ __launch_bounds__(256) void wconv_kernel(
    const float* __restrict__ w_in, bf16_t* __restrict__ wb)
{
    const int i = (blockIdx.x * 256 + threadIdx.x) * 4;
    f32x4 v = *(const f32x4*)(w_in + i);
    u32x2 p;
    p[0] = pk_bf16(v[0], v[1]);
    p[1] = pk_bf16(v[2], v[3]);
    *(u32x2*)&wb[i] = p;
}

// ---------------------------------------------------------------------------
// Kernel 1 (v4, unchanged from round 12): qkv = w_in @ x + b_in.
// Q -> q_r [8][4096][64] bf16 PRE-SCALED; K -> k_r; V -> v_t [8][64][4096].
// Grid: (64, 8), 256 threads.
// ---------------------------------------------------------------------------
__global__ __launch_bounds__(256, 4) void qkv_kernel(
    const float* __restrict__ x,
    const bf16_t* __restrict__ wb,
    const float* __restrict__ b_in,
    bf16_t* __restrict__ q_r,
    bf16_t* __restrict__ k_r,
    bf16_t* __restrict__ v_t)
{
    const int b    = blockIdx.y;
    const int n0   = blockIdx.x * 64;
    const int t    = threadIdx.x;
    const int lane = t & 63;
    const int wave = t >> 6;

    __shared__ bf16_t Xs[2][64][56];      // [buf][n][k], row stride 112B

    const float* xb = x + (size_t)b * 512 * 4096;

    const int c  = t >> 3;                // 0..31
    const int nb = (t & 7) * 8;           // 0..56

    float4 pv0, pv1;

    {
        const float* src = xb + (size_t)c * 4096 + n0 + nb;
        pv0 = *(const float4*)(src);
        pv1 = *(const float4*)(src + 4);
        Xs[0][nb + 0][c] = (bf16_t)pv0.x; Xs[0][nb + 1][c] = (bf16_t)pv0.y;
        Xs[0][nb + 2][c] = (bf16_t)pv0.z; Xs[0][nb + 3][c] = (bf16_t)pv0.w;
        Xs[0][nb + 4][c] = (bf16_t)pv1.x; Xs[0][nb + 5][c] = (bf16_t)pv1.y;
        Xs[0][nb + 6][c] = (bf16_t)pv1.z; Xs[0][nb + 7][c] = (bf16_t)pv1.w;
    }
    __syncthreads();

    f32x4 acc[3][4] = {};

    for (int kk = 0; kk < 16; ++kk) {
        const int cur = kk & 1;
        if (kk < 15) {
            const float* src = xb + (size_t)((kk + 1) * 32 + c) * 4096 + n0 + nb;
            pv0 = *(const float4*)(src);
            pv1 = *(const float4*)(src + 4);
        }

        bf16x8 bfr[4];
        #pragma unroll
        for (int nf = 0; nf < 4; ++nf)
            bfr[nf] = *(const bf16x8*)&Xs[cur][nf * 16 + (lane & 15)][(lane >> 4) * 8];

        #pragma unroll
        for (int mf = 0; mf < 3; ++mf) {
            const int m = wave * 48 + mf * 16 + (lane & 15);
            bf16x8 af = *(const bf16x8*)(wb + (size_t)m * 512 + kk * 32 + (lane >> 4) * 8);
            #pragma unroll
            for (int nf = 0; nf < 4; ++nf)
                acc[mf][nf] = MFMA16(af, bfr[nf], acc[mf][nf]);
        }

        if (kk < 15) {
            const int nxt = cur ^ 1;
            Xs[nxt][nb + 0][c] = (bf16_t)pv0.x; Xs[nxt][nb + 1][c] = (bf16_t)pv0.y;
            Xs[nxt][nb + 2][c] = (bf16_t)pv0.z; Xs[nxt][nb + 3][c] = (bf16_t)pv0.w;
            Xs[nxt][nb + 4][c] = (bf16_t)pv1.x; Xs[nxt][nb + 5][c] = (bf16_t)pv1.y;
            Xs[nxt][nb + 6][c] = (bf16_t)pv1.z; Xs[nxt][nb + 7][c] = (bf16_t)pv1.w;
        }
        __syncthreads();
    }

    #pragma unroll
    for (int mf = 0; mf < 3; ++mf) {
        const int mbase = wave * 48 + mf * 16;
        const int route = mbase >> 6;
        const int cloc  = (mbase & 63) + (lane >> 4) * 4;
        const int bbase = mbase + (lane >> 4) * 4;
        #pragma unroll
        for (int nf = 0; nf < 4; ++nf) {
            const int n = n0 + nf * 16 + (lane & 15);
            const float v0 = acc[mf][nf][0] + b_in[bbase + 0];
            const float v1 = acc[mf][nf][1] + b_in[bbase + 1];
            const float v2 = acc[mf][nf][2] + b_in[bbase + 2];
            const float v3 = acc[mf][nf][3] + b_in[bbase + 3];
            if (route == 0) {
                bf16_t* qp = &q_r[((size_t)b * 4096 + n) * 64 + cloc];
                qp[0] = (bf16_t)(v0 * QSCALE); qp[1] = (bf16_t)(v1 * QSCALE);
                qp[2] = (bf16_t)(v2 * QSCALE); qp[3] = (bf16_t)(v3 * QSCALE);
            } else if (route == 1) {
                bf16_t* kp = &k_r[((size_t)b * 4096 + n) * 64 + cloc];
                kp[0] = (bf16_t)v0; kp[1] = (bf16_t)v1;
                kp[2] = (bf16_t)v2; kp[3] = (bf16_t)v3;
            } else {
                v_t[((size_t)b * 64 + cloc + 0) * 4096 + n] = (bf16_t)v0;
                v_t[((size_t)b * 64 + cloc + 1) * 4096 + n] = (bf16_t)v1;
                v_t[((size_t)b * 64 + cloc + 2) * 4096 + n] = (bf16_t)v2;
                v_t[((size_t)b * 64 + cloc + 3) * 4096 + n] = (bf16_t)v3;
            }
        }
    }
}

// ---------------------------------------------------------------------------
// Kernel 2: flash attention PARTIAL — byte-identical to round 11 (measured
// best: 54.4 µs; setprio reverted). NSPLIT=4, 32 KB LDS, (256,2), no spill.
// ---------------------------------------------------------------------------
template <int NSPLIT>
__global__ __launch_bounds__(256, 2) void attn_partial_kernel(
    const bf16_t* __restrict__ q_r, const bf16_t* __restrict__ k_r,
    const bf16_t* __restrict__ v_t,
    bf16_t* __restrict__ Opart, float* __restrict__ ml)
{
    constexpr int KVLEN = 4096 / NSPLIT;
    constexpr int NT    = KVLEN / 64;

    const int b     = blockIdx.y;
    const int split = blockIdx.z;
    const int kv0   = split * KVLEN;
    const int t     = threadIdx.x;
    const int lane  = t & 63;
    const int wave  = t >> 6;
    const int lq    = lane & 31;
    const int hi    = lane >> 5;
    const int qA    = blockIdx.x * 256 + wave * 64 + lq;
    const int qB    = qA + 32;

    __shared__ bf16_t Ks[2][64 * 64];
    __shared__ bf16_t Vs[2][64 * 64];

    const int r8  = lane >> 3;
    const int csw = (lane & 7) ^ r8;
    const bf16_t* kb = k_r + (size_t)b * 4096 * 64;
    const bf16_t* vb = v_t + (size_t)b * 64 * 4096;

    auto STAGE = [&](int buf, int m0) {
        #pragma unroll
        for (int i = 0; i < 2; ++i) {
            const int rr = wave * 16 + i * 8;
            gload16(kb + (size_t)(m0 + rr + r8) * 64 + csw * 8, &Ks[buf][rr * 64]);
            gload16(vb + (size_t)(rr + r8) * 4096 + m0 + csw * 8, &Vs[buf][rr * 64]);
        }
    };

    bf16x8 qfA[4], qfB[4];
    {
        const bf16_t* qpA = q_r + ((size_t)b * 4096 + qA) * 64 + hi * 8;
        const bf16_t* qpB = q_r + ((size_t)b * 4096 + qB) * 64 + hi * 8;
        #pragma unroll
        for (int ks = 0; ks < 4; ++ks) {
            qfA[ks] = *(const bf16x8*)(qpA + ks * 16);
            qfB[ks] = *(const bf16x8*)(qpB + ks * 16);
        }
    }

    const bf16x8 vones = frag4(0x3F803F80u, 0x3F803F80u, 0x3F803F80u, 0x3F803F80u);

    f32x16 oaA0 = {}, oaA1 = {}, oaB0 = {}, oaB1 = {};
    f32x16 laccA = {};                    // l accumulators (only [0] meaningful)
    f32x16 laccB = {};
    float mA = -3.0e38f, mB = -3.0e38f;

    auto SMPV = [&](f32x16& s, float& m_run, f32x16& l_acc,
                    f32x16& o0, f32x16& o1,
                    const bf16x8 v00, const bf16x8 v01,
                    const bf16x8 v10, const bf16x8 v11) {
        {
            // max of 16 via nested triples (fuses to v_max3_f32)
            const float t0 = fmaxf(fmaxf(s[0],  s[1]),  s[2]);
            const float t1 = fmaxf(fmaxf(s[3],  s[4]),  s[5]);
            const float t2 = fmaxf(fmaxf(s[6],  s[7]),  s[8]);
            const float t3 = fmaxf(fmaxf(s[9],  s[10]), s[11]);
            const float t4 = fmaxf(fmaxf(s[12], s[13]), s[14]);
            const float u0 = fmaxf(fmaxf(t0, t1), t2);
            const float u1 = fmaxf(fmaxf(t3, t4), s[15]);
            float tm = fmaxf(u0, u1);
            tm = fmaxf(tm, __shfl_xor(tm, 32));
            if (__any(tm > m_run + 8.f)) {
                const float nm = fmaxf(m_run, tm);
                const float sc = __builtin_amdgcn_exp2f(m_run - nm);
                m_run = nm;
                l_acc[0] *= sc;
                #pragma unroll
                for (int r = 0; r < 16; ++r) { o0[r] *= sc; o1[r] *= sc; }
            }
        }
        #pragma unroll
        for (int r = 0; r < 16; ++r) s[r] = __builtin_amdgcn_exp2f(s[r] - m_run);

        // pack P -> bf16 B-frags; half-wave exchange via permlane32_swap
        unsigned w0 = pk_bf16(s[0],  s[1]),  w1 = pk_bf16(s[2],  s[3]);
        unsigned w2 = pk_bf16(s[4],  s[5]),  w3 = pk_bf16(s[6],  s[7]);
        unsigned w4 = pk_bf16(s[8],  s[9]),  w5 = pk_bf16(s[10], s[11]);
        unsigned w6 = pk_bf16(s[12], s[13]), w7 = pk_bf16(s[14], s[15]);
        asm("v_permlane32_swap_b32 %0, %1" : "+v"(w0), "+v"(w2));
        asm("v_permlane32_swap_b32 %0, %1" : "+v"(w1), "+v"(w3));
        asm("v_permlane32_swap_b32 %0, %1" : "+v"(w4), "+v"(w6));
        asm("v_permlane32_swap_b32 %0, %1" : "+v"(w5), "+v"(w7));
        const bf16x8 pf0 = frag4(w0, w1, w2, w3);
        const bf16x8 pf1 = frag4(w4, w5, w6, w7);

        // l row-sum + O update on the matrix pipe
        l_acc = MFMA32(vones, pf0, l_acc);
        l_acc = MFMA32(vones, pf1, l_acc);
        o0 = MFMA32(v00, pf0, o0);
        o0 = MFMA32(v01, pf1, o0);
        o1 = MFMA32(v10, pf0, o1);
        o1 = MFMA32(v11, pf1, o1);
    };

    STAGE(0, kv0);
    asm volatile("s_waitcnt vmcnt(0)" ::: "memory");
    __builtin_amdgcn_s_barrier();

    for (int tt = 0; tt < NT; ++tt) {
        const int cur = tt & 1;
        if (tt < NT - 1) STAGE(cur ^ 1, kv0 + (tt + 1) * 64);

        #pragma unroll
        for (int s = 0; s < 2; ++s) {
            bf16x8 kf[4];
            #pragma unroll
            for (int ks = 0; ks < 4; ++ks)
                kf[ks] = *(const bf16x8*)&Ks[cur][(s * 32 + lq) * 64 +
                                                  (((ks * 2 + hi) ^ (lq & 7)) * 8)];
            f32x16 s0 = {}, s1 = {};
            #pragma unroll
            for (int ks = 0; ks < 4; ++ks) {
                s0 = MFMA32(kf[ks], qfA[ks], s0);
                s1 = MFMA32(kf[ks], qfB[ks], s1);
            }
            const int K0 = s * 4 + hi;
            const int K1 = s * 4 + 2 + hi;
            const bf16x8 v00 = *(const bf16x8*)&Vs[cur][lq * 64 + ((K0 ^ (lq & 7)) * 8)];
            const bf16x8 v10 = *(const bf16x8*)&Vs[cur][(32 + lq) * 64 + ((K0 ^ (lq & 7)) * 8)];
            const bf16x8 v01 = *(const bf16x8*)&Vs[cur][lq * 64 + ((K1 ^ (lq & 7)) * 8)];
            const bf16x8 v11 = *(const bf16x8*)&Vs[cur][(32 + lq) * 64 + ((K1 ^ (lq & 7)) * 8)];

            SMPV(s0, mA, laccA, oaA0, oaA1, v00, v01, v10, v11);
            SMPV(s1, mB, laccB, oaB0, oaB1, v00, v01, v10, v11);
        }

        asm volatile("s_waitcnt vmcnt(0) lgkmcnt(0)" ::: "memory");
        __builtin_amdgcn_s_barrier();
    }

    auto EPI = [&](const f32x16& o_0, const f32x16& o_1, float l_run, int nq) {
        const float inv = 1.f / l_run;
        #pragma unroll
        for (int ct = 0; ct < 2; ++ct) {
            f32x16 o = ct ? o_1 : o_0;
            #pragma unroll
            for (int r = 0; r < 16; ++r) o[r] *= inv;
            unsigned w0 = pk_bf16(o[0],  o[1]),  w1 = pk_bf16(o[2],  o[3]);
            unsigned w2 = pk_bf16(o[4],  o[5]),  w3 = pk_bf16(o[6],  o[7]);
            unsigned w4 = pk_bf16(o[8],  o[9]),  w5 = pk_bf16(o[10], o[11]);
            unsigned w6 = pk_bf16(o[12], o[13]), w7 = pk_bf16(o[14], o[15]);
            asm("v_permlane32_swap_b32 %0, %1" : "+v"(w0), "+v"(w2));
            asm("v_permlane32_swap_b32 %0, %1" : "+v"(w1), "+v"(w3));
            asm("v_permlane32_swap_b32 %0, %1" : "+v"(w4), "+v"(w6));
            asm("v_permlane32_swap_b32 %0, %1" : "+v"(w5), "+v"(w7));
            bf16x8 ob0 = frag4(w0, w1, w2, w3);
            bf16x8 ob1 = frag4(w4, w5, w6, w7);
            bf16_t* op = Opart + (((size_t)(b * NSPLIT + split)) * 4096 + nq) * 64 + ct * 32;
            *(bf16x8*)(op + hi * 8)      = ob0;
            *(bf16x8*)(op + 16 + hi * 8) = ob1;
        }
    };
    EPI(oaA0, oaA1, laccA[0], qA);
    EPI(oaB0, oaB1, laccB[0], qB);

    if (hi == 0) {
        float2 va; va.x = mA; va.y = laccA[0];
        *(float2*)&ml[(((size_t)(b * NSPLIT + split)) * 4096 + qA) * 2] = va;
        float2 vbv; vbv.x = mB; vbv.y = laccB[0];
        *(float2*)&ml[(((size_t)(b * NSPLIT + split)) * 4096 + qB) * 2] = vbv;
    }
}

// ---------------------------------------------------------------------------
// Kernel 3 (v2): combine partials + out-proj + bias + skip.
// Grid: (128 q-tiles of 32, 8 batches) = 1024 blocks, 512 threads (8 waves).
// Each wave: 2 mt blocks (mt = wave*2 + i). T14: x loads issued BEFORE the
// MFMA chain of each mt block so HBM latency hides under compute.
// ---------------------------------------------------------------------------
template <int NSPLIT>
__global__ __launch_bounds__(512) void combine_kernel(
    const bf16_t* __restrict__ Opart, const float* __restrict__ ml,
    const float* __restrict__ x, const float* __restrict__ w_out,
    const float* __restrict__ b_out, float* __restrict__ y)
{
    const int b    = blockIdx.y;
    const int t    = threadIdx.x;
    const int lane = t & 63;
    const int wave = t >> 6;          // 0..7
    const int lq   = lane & 31;
    const int hi   = lane >> 5;
    const int nq   = blockIdx.x * 32 + lq;

    float coef[NSPLIT];
    {
        float m_s[NSPLIT], l_s[NSPLIT];
        #pragma unroll
        for (int s = 0; s < NSPLIT; ++s) {
            float2 v = *(const float2*)&ml[(((size_t)(b * NSPLIT + s)) * 4096 + nq) * 2];
            m_s[s] = v.x; l_s[s] = v.y;
        }
        float M = m_s[0];
        #pragma unroll
        for (int s = 1; s < NSPLIT; ++s) M = fmaxf(M, m_s[s]);
        float L = 0.f;
        #pragma unroll
        for (int s = 0; s < NSPLIT; ++s) {
            coef[s] = __builtin_amdgcn_exp2f(m_s[s] - M) * l_s[s];
            L += coef[s];
        }
        const float invL = 1.f / L;
        #pragma unroll
        for (int s = 0; s < NSPLIT; ++s) coef[s] *= invL;
    }

    bf16x8 obf[4];
    #pragma unroll
    for (int ks = 0; ks < 4; ++ks) {
        float a8[8] = {};
        #pragma unroll
        for (int s = 0; s < NSPLIT; ++s) {
            bf16x8 o = *(const bf16x8*)&Opart[
                (((size_t)(b * NSPLIT + s)) * 4096 + nq) * 64 + ks * 16 + hi * 8];
            #pragma unroll
            for (int j = 0; j < 8; ++j) a8[j] += coef[s] * (float)o[j];
        }
        obf[ks] = frag4(pk_bf16(a8[0], a8[1]), pk_bf16(a8[2], a8[3]),
                        pk_bf16(a8[4], a8[5]), pk_bf16(a8[6], a8[7]));
    }

    #pragma unroll 1
    for (int i = 0; i < 2; ++i) {
        const int mt = wave * 2 + i;
        // T14: issue skip-path x loads up front (latency hides under MFMA)
        float xv[16];
        size_t idxs[16];
        #pragma unroll
        for (int r = 0; r < 16; ++r) {
            const int m = mt * 32 + (r & 3) + 8 * (r >> 2) + 4 * hi;
            idxs[r] = ((size_t)b * 512 + m) * 4096 + nq;
            xv[r] = x[idxs[r]];
        }
        f32x16 acc = {};
        #pragma unroll
        for (int ks = 0; ks < 4; ++ks) {
            const float* wp = w_out + (size_t)(mt * 32 + lq) * 64 + ks * 16 + hi * 8;
            f32x4 a0 = *(const f32x4*)wp;
            f32x4 a1 = *(const f32x4*)(wp + 4);
            bf16x8 af = frag4(pk_bf16(a0[0], a0[1]), pk_bf16(a0[2], a0[3]),
                              pk_bf16(a1[0], a1[1]), pk_bf16(a1[2], a1[3]));
            acc = MFMA32(af, obf[ks], acc);
        }
        #pragma unroll
        for (int r = 0; r < 16; ++r) {
            const int m = mt * 32 + (r & 3) + 8 * (r >> 2) + 4 * hi;
            y[idxs[r]] = acc[r] + b_out[m] + xv[r];
        }
    }
}

// ---------------------------------------------------------------------------
extern "C" void kernel_launch(void* const* d_in, const int* in_sizes, int n_in,
                              void* d_out, int out_size, void* d_ws, size_t ws_size,
                              hipStream_t stream)
{
    const float* x     = (const float*)d_in[0];
    const float* w_in  = (const float*)d_in[1];
    const float* b_in  = (const float*)d_in[2];
    const float* w_out = (const float*)d_in[3];
    const float* b_out = (const float*)d_in[4];
    float* y = (float*)d_out;

    char* ws = (char*)d_ws;
    bf16_t* q_r   = (bf16_t*)(ws);                       // 4 MiB
    bf16_t* k_r   = (bf16_t*)(ws + 4194304);             // 4 MiB
    bf16_t* v_t   = (bf16_t*)(ws + 8388608);             // 4 MiB
    bf16_t* Opart = (bf16_t*)(ws + 12582912);            // 16 MiB (NSPLIT=4)
    float*  ml    = (float*)(ws + 12582912 + 16777216);  // 1 MiB
    bf16_t* wb    = (bf16_t*)(ws + 12582912 + 16777216 + 2097152);  // 192 KiB

    wconv_kernel<<<dim3(96), 256, 0, stream>>>(w_in, wb);
    qkv_kernel<<<dim3(64, 8), 256, 0, stream>>>(x, wb, b_in, q_r, k_r, v_t);
    attn_partial_kernel<4><<<dim3(16, 8, 4), 256, 0, stream>>>(q_r, k_r, v_t, Opart, ml);
    combine_kernel<4><<<dim3(128, 8), 512, 0, stream>>>(Opart, ml, x, w_out, b_out, y);
}

// Round 14
// 122.133 us; speedup vs baseline: 1.0343x; 1.0343x over previous
//
#include <hip/hip_runtime.h>
#include <hip/hip_bf16.h>

typedef __bf16 bf16_t;
typedef __bf16 bf16x8 __attribute__((ext_vector_type(8)));
typedef float f32x4 __attribute__((ext_vector_type(4)));
typedef float f32x16 __attribute__((ext_vector_type(16)));
typedef unsigned int u32x2 __attribute__((ext_vector_type(2)));
typedef unsigned int u32x4 __attribute__((ext_vector_type(4)));

#define MFMA16(A,B,C) __builtin_amdgcn_mfma_f32_16x16x32_bf16(A,B,C,0,0,0)
#define MFMA32(A,B,C) __builtin_amdgcn_mfma_f32_32x32x16_bf16(A,B,C,0,0,0)

// exp(s/8) computed as exp2(s * 0.125*log2(e)); the scale is folded into Q.
#define QSCALE 0.18033688011112042f

__device__ inline unsigned pk_bf16(float lo, float hi) {
  unsigned r;
  asm("v_cvt_pk_bf16_f32 %0, %1, %2" : "=v"(r) : "v"(lo), "v"(hi));
  return r;
}
__device__ inline bf16x8 frag4(unsigned a, unsigned b, unsigned c, unsigned d) {
  union { u32x4 u; bf16x8 f; } x;
  x.u = (u32x4){a, b, c, d};
  return x.f;
}
__device__ inline void gload16(const bf16_t* g, const bf16_t* l) {
  __builtin_amdgcn_global_load_lds(
      (const __attribute__((address_space(1))) unsigned int*)g,
      (__attribute__((address_space(3))) unsigned int*)l, 16, 0, 0);
}

// ---------------------------------------------------------------------------
// Kernel 0: one-time w_in fp32 -> bf16 conversion (192*512 = 98304 elems).
// ---------------------------------------------------------------------------
__global__ __launch_bounds__(256) void wconv_kernel(
    const float* __restrict__ w_in, bf16_t* __restrict__ wb)
{
    const int i = (blockIdx.x * 256 + threadIdx.x) * 4;
    f32x4 v = *(const f32x4*)(w_in + i);
    u32x2 p;
    p[0] = pk_bf16(v[0], v[1]);
    p[1] = pk_bf16(v[2], v[3]);
    *(u32x2*)&wb[i] = p;
}

// ---------------------------------------------------------------------------
// Kernel 1 (v4, unchanged from round 12): qkv = w_in @ x + b_in.
// Q -> q_r [8][4096][64] bf16 PRE-SCALED; K -> k_r; V -> v_t [8][64][4096].
// Grid: (64, 8), 256 threads.
// ---------------------------------------------------------------------------
__global__ __launch_bounds__(256, 4) void qkv_kernel(
    const float* __restrict__ x,
    const bf16_t* __restrict__ wb,
    const float* __restrict__ b_in,
    bf16_t* __restrict__ q_r,
    bf16_t* __restrict__ k_r,
    bf16_t* __restrict__ v_t)
{
    const int b    = blockIdx.y;
    const int n0   = blockIdx.x * 64;
    const int t    = threadIdx.x;
    const int lane = t & 63;
    const int wave = t >> 6;

    __shared__ bf16_t Xs[2][64][56];      // [buf][n][k], row stride 112B

    const float* xb = x + (size_t)b * 512 * 4096;

    const int c  = t >> 3;                // 0..31
    const int nb = (t & 7) * 8;           // 0..56

    float4 pv0, pv1;

    {
        const float* src = xb + (size_t)c * 4096 + n0 + nb;
        pv0 = *(const float4*)(src);
        pv1 = *(const float4*)(src + 4);
        Xs[0][nb + 0][c] = (bf16_t)pv0.x; Xs[0][nb + 1][c] = (bf16_t)pv0.y;
        Xs[0][nb + 2][c] = (bf16_t)pv0.z; Xs[0][nb + 3][c] = (bf16_t)pv0.w;
        Xs[0][nb + 4][c] = (bf16_t)pv1.x; Xs[0][nb + 5][c] = (bf16_t)pv1.y;
        Xs[0][nb + 6][c] = (bf16_t)pv1.z; Xs[0][nb + 7][c] = (bf16_t)pv1.w;
    }
    __syncthreads();

    f32x4 acc[3][4] = {};

    for (int kk = 0; kk < 16; ++kk) {
        const int cur = kk & 1;
        if (kk < 15) {
            const float* src = xb + (size_t)((kk + 1) * 32 + c) * 4096 + n0 + nb;
            pv0 = *(const float4*)(src);
            pv1 = *(const float4*)(src + 4);
        }

        bf16x8 bfr[4];
        #pragma unroll
        for (int nf = 0; nf < 4; ++nf)
            bfr[nf] = *(const bf16x8*)&Xs[cur][nf * 16 + (lane & 15)][(lane >> 4) * 8];

        #pragma unroll
        for (int mf = 0; mf < 3; ++mf) {
            const int m = wave * 48 + mf * 16 + (lane & 15);
            bf16x8 af = *(const bf16x8*)(wb + (size_t)m * 512 + kk * 32 + (lane >> 4) * 8);
            #pragma unroll
            for (int nf = 0; nf < 4; ++nf)
                acc[mf][nf] = MFMA16(af, bfr[nf], acc[mf][nf]);
        }

        if (kk < 15) {
            const int nxt = cur ^ 1;
            Xs[nxt][nb + 0][c] = (bf16_t)pv0.x; Xs[nxt][nb + 1][c] = (bf16_t)pv0.y;
            Xs[nxt][nb + 2][c] = (bf16_t)pv0.z; Xs[nxt][nb + 3][c] = (bf16_t)pv0.w;
            Xs[nxt][nb + 4][c] = (bf16_t)pv1.x; Xs[nxt][nb + 5][c] = (bf16_t)pv1.y;
            Xs[nxt][nb + 6][c] = (bf16_t)pv1.z; Xs[nxt][nb + 7][c] = (bf16_t)pv1.w;
        }
        __syncthreads();
    }

    #pragma unroll
    for (int mf = 0; mf < 3; ++mf) {
        const int mbase = wave * 48 + mf * 16;
        const int route = mbase >> 6;
        const int cloc  = (mbase & 63) + (lane >> 4) * 4;
        const int bbase = mbase + (lane >> 4) * 4;
        #pragma unroll
        for (int nf = 0; nf < 4; ++nf) {
            const int n = n0 + nf * 16 + (lane & 15);
            const float v0 = acc[mf][nf][0] + b_in[bbase + 0];
            const float v1 = acc[mf][nf][1] + b_in[bbase + 1];
            const float v2 = acc[mf][nf][2] + b_in[bbase + 2];
            const float v3 = acc[mf][nf][3] + b_in[bbase + 3];
            if (route == 0) {
                bf16_t* qp = &q_r[((size_t)b * 4096 + n) * 64 + cloc];
                qp[0] = (bf16_t)(v0 * QSCALE); qp[1] = (bf16_t)(v1 * QSCALE);
                qp[2] = (bf16_t)(v2 * QSCALE); qp[3] = (bf16_t)(v3 * QSCALE);
            } else if (route == 1) {
                bf16_t* kp = &k_r[((size_t)b * 4096 + n) * 64 + cloc];
                kp[0] = (bf16_t)v0; kp[1] = (bf16_t)v1;
                kp[2] = (bf16_t)v2; kp[3] = (bf16_t)v3;
            } else {
                v_t[((size_t)b * 64 + cloc + 0) * 4096 + n] = (bf16_t)v0;
                v_t[((size_t)b * 64 + cloc + 1) * 4096 + n] = (bf16_t)v1;
                v_t[((size_t)b * 64 + cloc + 2) * 4096 + n] = (bf16_t)v2;
                v_t[((size_t)b * 64 + cloc + 3) * 4096 + n] = (bf16_t)v3;
            }
        }
    }
}

// ---------------------------------------------------------------------------
// Kernel 2: flash attention PARTIAL — measured-best (round 11/13): NSPLIT=4,
// 32 KB LDS, (256,2), permlane pack, ones-MFMA l-sum, max3 tree, no setprio.
// ---------------------------------------------------------------------------
template <int NSPLIT>
__global__ __launch_bounds__(256, 2) void attn_partial_kernel(
    const bf16_t* __restrict__ q_r, const bf16_t* __restrict__ k_r,
    const bf16_t* __restrict__ v_t,
    bf16_t* __restrict__ Opart, float* __restrict__ ml)
{
    constexpr int KVLEN = 4096 / NSPLIT;
    constexpr int NT    = KVLEN / 64;

    const int b     = blockIdx.y;
    const int split = blockIdx.z;
    const int kv0   = split * KVLEN;
    const int t     = threadIdx.x;
    const int lane  = t & 63;
    const int wave  = t >> 6;
    const int lq    = lane & 31;
    const int hi    = lane >> 5;
    const int qA    = blockIdx.x * 256 + wave * 64 + lq;
    const int qB    = qA + 32;

    __shared__ bf16_t Ks[2][64 * 64];
    __shared__ bf16_t Vs[2][64 * 64];

    const int r8  = lane >> 3;
    const int csw = (lane & 7) ^ r8;
    const bf16_t* kb = k_r + (size_t)b * 4096 * 64;
    const bf16_t* vb = v_t + (size_t)b * 64 * 4096;

    auto STAGE = [&](int buf, int m0) {
        #pragma unroll
        for (int i = 0; i < 2; ++i) {
            const int rr = wave * 16 + i * 8;
            gload16(kb + (size_t)(m0 + rr + r8) * 64 + csw * 8, &Ks[buf][rr * 64]);
            gload16(vb + (size_t)(rr + r8) * 4096 + m0 + csw * 8, &Vs[buf][rr * 64]);
        }
    };

    bf16x8 qfA[4], qfB[4];
    {
        const bf16_t* qpA = q_r + ((size_t)b * 4096 + qA) * 64 + hi * 8;
        const bf16_t* qpB = q_r + ((size_t)b * 4096 + qB) * 64 + hi * 8;
        #pragma unroll
        for (int ks = 0; ks < 4; ++ks) {
            qfA[ks] = *(const bf16x8*)(qpA + ks * 16);
            qfB[ks] = *(const bf16x8*)(qpB + ks * 16);
        }
    }

    const bf16x8 vones = frag4(0x3F803F80u, 0x3F803F80u, 0x3F803F80u, 0x3F803F80u);

    f32x16 oaA0 = {}, oaA1 = {}, oaB0 = {}, oaB1 = {};
    f32x16 laccA = {};                    // l accumulators (only [0] meaningful)
    f32x16 laccB = {};
    float mA = -3.0e38f, mB = -3.0e38f;

    auto SMPV = [&](f32x16& s, float& m_run, f32x16& l_acc,
                    f32x16& o0, f32x16& o1,
                    const bf16x8 v00, const bf16x8 v01,
                    const bf16x8 v10, const bf16x8 v11) {
        {
            // max of 16 via nested triples (fuses to v_max3_f32)
            const float t0 = fmaxf(fmaxf(s[0],  s[1]),  s[2]);
            const float t1 = fmaxf(fmaxf(s[3],  s[4]),  s[5]);
            const float t2 = fmaxf(fmaxf(s[6],  s[7]),  s[8]);
            const float t3 = fmaxf(fmaxf(s[9],  s[10]), s[11]);
            const float t4 = fmaxf(fmaxf(s[12], s[13]), s[14]);
            const float u0 = fmaxf(fmaxf(t0, t1), t2);
            const float u1 = fmaxf(fmaxf(t3, t4), s[15]);
            float tm = fmaxf(u0, u1);
            tm = fmaxf(tm, __shfl_xor(tm, 32));
            if (__any(tm > m_run + 8.f)) {
                const float nm = fmaxf(m_run, tm);
                const float sc = __builtin_amdgcn_exp2f(m_run - nm);
                m_run = nm;
                l_acc[0] *= sc;
                #pragma unroll
                for (int r = 0; r < 16; ++r) { o0[r] *= sc; o1[r] *= sc; }
            }
        }
        #pragma unroll
        for (int r = 0; r < 16; ++r) s[r] = __builtin_amdgcn_exp2f(s[r] - m_run);

        // pack P -> bf16 B-frags; half-wave exchange via permlane32_swap
        unsigned w0 = pk_bf16(s[0],  s[1]),  w1 = pk_bf16(s[2],  s[3]);
        unsigned w2 = pk_bf16(s[4],  s[5]),  w3 = pk_bf16(s[6],  s[7]);
        unsigned w4 = pk_bf16(s[8],  s[9]),  w5 = pk_bf16(s[10], s[11]);
        unsigned w6 = pk_bf16(s[12], s[13]), w7 = pk_bf16(s[14], s[15]);
        asm("v_permlane32_swap_b32 %0, %1" : "+v"(w0), "+v"(w2));
        asm("v_permlane32_swap_b32 %0, %1" : "+v"(w1), "+v"(w3));
        asm("v_permlane32_swap_b32 %0, %1" : "+v"(w4), "+v"(w6));
        asm("v_permlane32_swap_b32 %0, %1" : "+v"(w5), "+v"(w7));
        const bf16x8 pf0 = frag4(w0, w1, w2, w3);
        const bf16x8 pf1 = frag4(w4, w5, w6, w7);

        // l row-sum + O update on the matrix pipe
        l_acc = MFMA32(vones, pf0, l_acc);
        l_acc = MFMA32(vones, pf1, l_acc);
        o0 = MFMA32(v00, pf0, o0);
        o0 = MFMA32(v01, pf1, o0);
        o1 = MFMA32(v10, pf0, o1);
        o1 = MFMA32(v11, pf1, o1);
    };

    STAGE(0, kv0);
    asm volatile("s_waitcnt vmcnt(0)" ::: "memory");
    __builtin_amdgcn_s_barrier();

    for (int tt = 0; tt < NT; ++tt) {
        const int cur = tt & 1;
        if (tt < NT - 1) STAGE(cur ^ 1, kv0 + (tt + 1) * 64);

        #pragma unroll
        for (int s = 0; s < 2; ++s) {
            bf16x8 kf[4];
            #pragma unroll
            for (int ks = 0; ks < 4; ++ks)
                kf[ks] = *(const bf16x8*)&Ks[cur][(s * 32 + lq) * 64 +
                                                  (((ks * 2 + hi) ^ (lq & 7)) * 8)];
            f32x16 s0 = {}, s1 = {};
            #pragma unroll
            for (int ks = 0; ks < 4; ++ks) {
                s0 = MFMA32(kf[ks], qfA[ks], s0);
                s1 = MFMA32(kf[ks], qfB[ks], s1);
            }
            const int K0 = s * 4 + hi;
            const int K1 = s * 4 + 2 + hi;
            const bf16x8 v00 = *(const bf16x8*)&Vs[cur][lq * 64 + ((K0 ^ (lq & 7)) * 8)];
            const bf16x8 v10 = *(const bf16x8*)&Vs[cur][(32 + lq) * 64 + ((K0 ^ (lq & 7)) * 8)];
            const bf16x8 v01 = *(const bf16x8*)&Vs[cur][lq * 64 + ((K1 ^ (lq & 7)) * 8)];
            const bf16x8 v11 = *(const bf16x8*)&Vs[cur][(32 + lq) * 64 + ((K1 ^ (lq & 7)) * 8)];

            SMPV(s0, mA, laccA, oaA0, oaA1, v00, v01, v10, v11);
            SMPV(s1, mB, laccB, oaB0, oaB1, v00, v01, v10, v11);
        }

        asm volatile("s_waitcnt vmcnt(0) lgkmcnt(0)" ::: "memory");
        __builtin_amdgcn_s_barrier();
    }

    auto EPI = [&](const f32x16& o_0, const f32x16& o_1, float l_run, int nq) {
        const float inv = 1.f / l_run;
        #pragma unroll
        for (int ct = 0; ct < 2; ++ct) {
            f32x16 o = ct ? o_1 : o_0;
            #pragma unroll
            for (int r = 0; r < 16; ++r) o[r] *= inv;
            unsigned w0 = pk_bf16(o[0],  o[1]),  w1 = pk_bf16(o[2],  o[3]);
            unsigned w2 = pk_bf16(o[4],  o[5]),  w3 = pk_bf16(o[6],  o[7]);
            unsigned w4 = pk_bf16(o[8],  o[9]),  w5 = pk_bf16(o[10], o[11]);
            unsigned w6 = pk_bf16(o[12], o[13]), w7 = pk_bf16(o[14], o[15]);
            asm("v_permlane32_swap_b32 %0, %1" : "+v"(w0), "+v"(w2));
            asm("v_permlane32_swap_b32 %0, %1" : "+v"(w1), "+v"(w3));
            asm("v_permlane32_swap_b32 %0, %1" : "+v"(w4), "+v"(w6));
            asm("v_permlane32_swap_b32 %0, %1" : "+v"(w5), "+v"(w7));
            bf16x8 ob0 = frag4(w0, w1, w2, w3);
            bf16x8 ob1 = frag4(w4, w5, w6, w7);
            bf16_t* op = Opart + (((size_t)(b * NSPLIT + split)) * 4096 + nq) * 64 + ct * 32;
            *(bf16x8*)(op + hi * 8)      = ob0;
            *(bf16x8*)(op + 16 + hi * 8) = ob1;
        }
    };
    EPI(oaA0, oaA1, laccA[0], qA);
    EPI(oaB0, oaB1, laccB[0], qB);

    if (hi == 0) {
        float2 va; va.x = mA; va.y = laccA[0];
        *(float2*)&ml[(((size_t)(b * NSPLIT + split)) * 4096 + qA) * 2] = va;
        float2 vbv; vbv.x = mB; vbv.y = laccB[0];
        *(float2*)&ml[(((size_t)(b * NSPLIT + split)) * 4096 + qB) * 2] = vbv;
    }
}

// ---------------------------------------------------------------------------
// Kernel 3 (v1, round-12 measured-best): combine partials + out-proj + skip.
// Grid: (64 q-tiles of 64, 8 batches) = 512 blocks, 512 threads (8 waves).
// ---------------------------------------------------------------------------
template <int NSPLIT>
__global__ __launch_bounds__(512) void combine_kernel(
    const bf16_t* __restrict__ Opart, const float* __restrict__ ml,
    const float* __restrict__ x, const float* __restrict__ w_out,
    const float* __restrict__ b_out, float* __restrict__ y)
{
    const int b    = blockIdx.y;
    const int t    = threadIdx.x;
    const int lane = t & 63;
    const int wave = t >> 6;          // 0..7
    const int lq   = lane & 31;
    const int hi   = lane >> 5;
    const int group = wave >> 2;      // 0..1
    const int nq   = blockIdx.x * 64 + group * 32 + lq;

    float coef[NSPLIT];
    {
        float m_s[NSPLIT], l_s[NSPLIT];
        #pragma unroll
        for (int s = 0; s < NSPLIT; ++s) {
            float2 v = *(const float2*)&ml[(((size_t)(b * NSPLIT + s)) * 4096 + nq) * 2];
            m_s[s] = v.x; l_s[s] = v.y;
        }
        float M = m_s[0];
        #pragma unroll
        for (int s = 1; s < NSPLIT; ++s) M = fmaxf(M, m_s[s]);
        float L = 0.f;
        #pragma unroll
        for (int s = 0; s < NSPLIT; ++s) {
            coef[s] = __builtin_amdgcn_exp2f(m_s[s] - M) * l_s[s];
            L += coef[s];
        }
        const float invL = 1.f / L;
        #pragma unroll
        for (int s = 0; s < NSPLIT; ++s) coef[s] *= invL;
    }

    bf16x8 obf[4];
    #pragma unroll
    for (int ks = 0; ks < 4; ++ks) {
        float a8[8] = {};
        #pragma unroll
        for (int s = 0; s < NSPLIT; ++s) {
            bf16x8 o = *(const bf16x8*)&Opart[
                (((size_t)(b * NSPLIT + s)) * 4096 + nq) * 64 + ks * 16 + hi * 8];
            #pragma unroll
            for (int j = 0; j < 8; ++j) a8[j] += coef[s] * (float)o[j];
        }
        obf[ks] = frag4(pk_bf16(a8[0], a8[1]), pk_bf16(a8[2], a8[3]),
                        pk_bf16(a8[4], a8[5]), pk_bf16(a8[6], a8[7]));
    }

    #pragma unroll 1
    for (int i = 0; i < 4; ++i) {
        const int mt = (wave & 3) * 4 + i;
        f32x16 acc = {};
        #pragma unroll
        for (int ks = 0; ks < 4; ++ks) {
            const float* wp = w_out + (size_t)(mt * 32 + lq) * 64 + ks * 16 + hi * 8;
            f32x4 a0 = *(const f32x4*)wp;
            f32x4 a1 = *(const f32x4*)(wp + 4);
            bf16x8 af = frag4(pk_bf16(a0[0], a0[1]), pk_bf16(a0[2], a0[3]),
                              pk_bf16(a1[0], a1[1]), pk_bf16(a1[2], a1[3]));
            acc = MFMA32(af, obf[ks], acc);
        }
        #pragma unroll
        for (int r = 0; r < 16; ++r) {
            const int m = mt * 32 + (r & 3) + 8 * (r >> 2) + 4 * hi;
            const size_t idx = ((size_t)b * 512 + m) * 4096 + nq;
            y[idx] = acc[r] + b_out[m] + x[idx];
        }
    }
}

// ---------------------------------------------------------------------------
extern "C" void kernel_launch(void* const* d_in, const int* in_sizes, int n_in,
                              void* d_out, int out_size, void* d_ws, size_t ws_size,
                              hipStream_t stream)
{
    const float* x     = (const float*)d_in[0];
    const float* w_in  = (const float*)d_in[1];
    const float* b_in  = (const float*)d_in[2];
    const float* w_out = (const float*)d_in[3];
    const float* b_out = (const float*)d_in[4];
    float* y = (float*)d_out;

    char* ws = (char*)d_ws;
    bf16_t* q_r   = (bf16_t*)(ws);                       // 4 MiB
    bf16_t* k_r   = (bf16_t*)(ws + 4194304);             // 4 MiB
    bf16_t* v_t   = (bf16_t*)(ws + 8388608);             // 4 MiB
    bf16_t* Opart = (bf16_t*)(ws + 12582912);            // 16 MiB (NSPLIT=4)
    float*  ml    = (float*)(ws + 12582912 + 16777216);  // 1 MiB
    bf16_t* wb    = (bf16_t*)(ws + 12582912 + 16777216 + 2097152);  // 192 KiB

    wconv_kernel<<<dim3(96), 256, 0, stream>>>(w_in, wb);
    qkv_kernel<<<dim3(64, 8), 256, 0, stream>>>(x, wb, b_in, q_r, k_r, v_t);
    attn_partial_kernel<4><<<dim3(16, 8, 4), 256, 0, stream>>>(q_r, k_r, v_t, Opart, ml);
    combine_kernel<4><<<dim3(64, 8), 512, 0, stream>>>(Opart, ml, x, w_out, b_out, y);
}

// Round 15
// 120.317 us; speedup vs baseline: 1.0499x; 1.0151x over previous
//
#include <hip/hip_runtime.h>
#include <hip/hip_bf16.h>

typedef __bf16 bf16_t;
typedef __bf16 bf16x8 __attribute__((ext_vector_type(8)));
typedef float f32x4 __attribute__((ext_vector_type(4)));
typedef float f32x16 __attribute__((ext_vector_type(16)));
typedef unsigned int u32x2 __attribute__((ext_vector_type(2)));
typedef unsigned int u32x4 __attribute__((ext_vector_type(4)));

#define MFMA16(A,B,C) __builtin_amdgcn_mfma_f32_16x16x32_bf16(A,B,C,0,0,0)
#define MFMA32(A,B,C) __builtin_amdgcn_mfma_f32_32x32x16_bf16(A,B,C,0,0,0)

// exp(s/8) computed as exp2(s * 0.125*log2(e)); the scale is folded into Q.
#define QSCALE 0.18033688011112042f

__device__ inline unsigned pk_bf16(float lo, float hi) {
  unsigned r;
  asm("v_cvt_pk_bf16_f32 %0, %1, %2" : "=v"(r) : "v"(lo), "v"(hi));
  return r;
}
__device__ inline bf16x8 frag4(unsigned a, unsigned b, unsigned c, unsigned d) {
  union { u32x4 u; bf16x8 f; } x;
  x.u = (u32x4){a, b, c, d};
  return x.f;
}
__device__ inline void gload16(const bf16_t* g, const bf16_t* l) {
  __builtin_amdgcn_global_load_lds(
      (const __attribute__((address_space(1))) unsigned int*)g,
      (__attribute__((address_space(3))) unsigned int*)l, 16, 0, 0);
}

// ---------------------------------------------------------------------------
// Kernel 0: one-time w_in fp32 -> bf16 conversion (192*512 = 98304 elems).
// ---------------------------------------------------------------------------
__global__ __launch_bounds__(256) void wconv_kernel(
    const float* __restrict__ w_in, bf16_t* __restrict__ wb)
{
    const int i = (blockIdx.x * 256 + threadIdx.x) * 4;
    f32x4 v = *(const f32x4*)(w_in + i);
    u32x2 p;
    p[0] = pk_bf16(v[0], v[1]);
    p[1] = pk_bf16(v[2], v[3]);
    *(u32x2*)&wb[i] = p;
}

// ---------------------------------------------------------------------------
// Kernel 1 (v5): qkv = w_in @ x + b_in.
// v5 change: XOR-swizzled transposed staging — element (n,c) stored at
// Xs[n][c ^ 8*((n>>3)&3)]. Write side: (n>>3)&3 == t&3 for all 8 rows a
// thread writes -> banks spread 16-way -> ~4-way. Read side: chunk index
// XORed per row; still 16B-aligned contiguous, 2-way (free) conflicts.
// Q -> q_r [8][4096][64] bf16 PRE-SCALED; K -> k_r; V -> v_t [8][64][4096].
// Grid: (64, 8), 256 threads.
// ---------------------------------------------------------------------------
__global__ __launch_bounds__(256, 4) void qkv_kernel(
    const float* __restrict__ x,
    const bf16_t* __restrict__ wb,
    const float* __restrict__ b_in,
    bf16_t* __restrict__ q_r,
    bf16_t* __restrict__ k_r,
    bf16_t* __restrict__ v_t)
{
    const int b    = blockIdx.y;
    const int n0   = blockIdx.x * 64;
    const int t    = threadIdx.x;
    const int lane = t & 63;
    const int wave = t >> 6;

    __shared__ bf16_t Xs[2][64][56];      // [buf][n][k-swizzled], stride 112B

    const float* xb = x + (size_t)b * 512 * 4096;

    const int c  = t >> 3;                // 0..31 (k-row this thread stages)
    const int nb = (t & 7) * 8;           // n-octet base
    const int cs = c ^ (8 * (t & 3));     // swizzled column ((n>>3)&3 == t&3)

    float4 pv0, pv1;

    {
        const float* src = xb + (size_t)c * 4096 + n0 + nb;
        pv0 = *(const float4*)(src);
        pv1 = *(const float4*)(src + 4);
        Xs[0][nb + 0][cs] = (bf16_t)pv0.x; Xs[0][nb + 1][cs] = (bf16_t)pv0.y;
        Xs[0][nb + 2][cs] = (bf16_t)pv0.z; Xs[0][nb + 3][cs] = (bf16_t)pv0.w;
        Xs[0][nb + 4][cs] = (bf16_t)pv1.x; Xs[0][nb + 5][cs] = (bf16_t)pv1.y;
        Xs[0][nb + 6][cs] = (bf16_t)pv1.z; Xs[0][nb + 7][cs] = (bf16_t)pv1.w;
    }
    __syncthreads();

    f32x4 acc[3][4] = {};

    for (int kk = 0; kk < 16; ++kk) {
        const int cur = kk & 1;
        if (kk < 15) {
            const float* src = xb + (size_t)((kk + 1) * 32 + c) * 4096 + n0 + nb;
            pv0 = *(const float4*)(src);
            pv1 = *(const float4*)(src + 4);
        }

        bf16x8 bfr[4];
        #pragma unroll
        for (int nf = 0; nf < 4; ++nf) {
            const int n_ = nf * 16 + (lane & 15);
            const int ch = ((lane >> 4) * 8) ^ (8 * ((n_ >> 3) & 3));
            bfr[nf] = *(const bf16x8*)&Xs[cur][n_][ch];
        }

        #pragma unroll
        for (int mf = 0; mf < 3; ++mf) {
            const int m = wave * 48 + mf * 16 + (lane & 15);
            bf16x8 af = *(const bf16x8*)(wb + (size_t)m * 512 + kk * 32 + (lane >> 4) * 8);
            #pragma unroll
            for (int nf = 0; nf < 4; ++nf)
                acc[mf][nf] = MFMA16(af, bfr[nf], acc[mf][nf]);
        }

        if (kk < 15) {
            const int nxt = cur ^ 1;
            Xs[nxt][nb + 0][cs] = (bf16_t)pv0.x; Xs[nxt][nb + 1][cs] = (bf16_t)pv0.y;
            Xs[nxt][nb + 2][cs] = (bf16_t)pv0.z; Xs[nxt][nb + 3][cs] = (bf16_t)pv0.w;
            Xs[nxt][nb + 4][cs] = (bf16_t)pv1.x; Xs[nxt][nb + 5][cs] = (bf16_t)pv1.y;
            Xs[nxt][nb + 6][cs] = (bf16_t)pv1.z; Xs[nxt][nb + 7][cs] = (bf16_t)pv1.w;
        }
        __syncthreads();
    }

    #pragma unroll
    for (int mf = 0; mf < 3; ++mf) {
        const int mbase = wave * 48 + mf * 16;
        const int route = mbase >> 6;
        const int cloc  = (mbase & 63) + (lane >> 4) * 4;
        const int bbase = mbase + (lane >> 4) * 4;
        #pragma unroll
        for (int nf = 0; nf < 4; ++nf) {
            const int n = n0 + nf * 16 + (lane & 15);
            const float v0 = acc[mf][nf][0] + b_in[bbase + 0];
            const float v1 = acc[mf][nf][1] + b_in[bbase + 1];
            const float v2 = acc[mf][nf][2] + b_in[bbase + 2];
            const float v3 = acc[mf][nf][3] + b_in[bbase + 3];
            if (route == 0) {
                bf16_t* qp = &q_r[((size_t)b * 4096 + n) * 64 + cloc];
                qp[0] = (bf16_t)(v0 * QSCALE); qp[1] = (bf16_t)(v1 * QSCALE);
                qp[2] = (bf16_t)(v2 * QSCALE); qp[3] = (bf16_t)(v3 * QSCALE);
            } else if (route == 1) {
                bf16_t* kp = &k_r[((size_t)b * 4096 + n) * 64 + cloc];
                kp[0] = (bf16_t)v0; kp[1] = (bf16_t)v1;
                kp[2] = (bf16_t)v2; kp[3] = (bf16_t)v3;
            } else {
                v_t[((size_t)b * 64 + cloc + 0) * 4096 + n] = (bf16_t)v0;
                v_t[((size_t)b * 64 + cloc + 1) * 4096 + n] = (bf16_t)v1;
                v_t[((size_t)b * 64 + cloc + 2) * 4096 + n] = (bf16_t)v2;
                v_t[((size_t)b * 64 + cloc + 3) * 4096 + n] = (bf16_t)v3;
            }
        }
    }
}

// ---------------------------------------------------------------------------
// Kernel 2: flash attention PARTIAL — measured-best (rounds 11/13/14),
// byte-identical. NSPLIT=4, 32 KB LDS, (256,2), permlane pack, ones-MFMA
// l-sum, max3 tree, no setprio.
// ---------------------------------------------------------------------------
template <int NSPLIT>
__global__ __launch_bounds__(256, 2) void attn_partial_kernel(
    const bf16_t* __restrict__ q_r, const bf16_t* __restrict__ k_r,
    const bf16_t* __restrict__ v_t,
    bf16_t* __restrict__ Opart, float* __restrict__ ml)
{
    constexpr int KVLEN = 4096 / NSPLIT;
    constexpr int NT    = KVLEN / 64;

    const int b     = blockIdx.y;
    const int split = blockIdx.z;
    const int kv0   = split * KVLEN;
    const int t     = threadIdx.x;
    const int lane  = t & 63;
    const int wave  = t >> 6;
    const int lq    = lane & 31;
    const int hi    = lane >> 5;
    const int qA    = blockIdx.x * 256 + wave * 64 + lq;
    const int qB    = qA + 32;

    __shared__ bf16_t Ks[2][64 * 64];
    __shared__ bf16_t Vs[2][64 * 64];

    const int r8  = lane >> 3;
    const int csw = (lane & 7) ^ r8;
    const bf16_t* kb = k_r + (size_t)b * 4096 * 64;
    const bf16_t* vb = v_t + (size_t)b * 64 * 4096;

    auto STAGE = [&](int buf, int m0) {
        #pragma unroll
        for (int i = 0; i < 2; ++i) {
            const int rr = wave * 16 + i * 8;
            gload16(kb + (size_t)(m0 + rr + r8) * 64 + csw * 8, &Ks[buf][rr * 64]);
            gload16(vb + (size_t)(rr + r8) * 4096 + m0 + csw * 8, &Vs[buf][rr * 64]);
        }
    };

    bf16x8 qfA[4], qfB[4];
    {
        const bf16_t* qpA = q_r + ((size_t)b * 4096 + qA) * 64 + hi * 8;
        const bf16_t* qpB = q_r + ((size_t)b * 4096 + qB) * 64 + hi * 8;
        #pragma unroll
        for (int ks = 0; ks < 4; ++ks) {
            qfA[ks] = *(const bf16x8*)(qpA + ks * 16);
            qfB[ks] = *(const bf16x8*)(qpB + ks * 16);
        }
    }

    const bf16x8 vones = frag4(0x3F803F80u, 0x3F803F80u, 0x3F803F80u, 0x3F803F80u);

    f32x16 oaA0 = {}, oaA1 = {}, oaB0 = {}, oaB1 = {};
    f32x16 laccA = {};                    // l accumulators (only [0] meaningful)
    f32x16 laccB = {};
    float mA = -3.0e38f, mB = -3.0e38f;

    auto SMPV = [&](f32x16& s, float& m_run, f32x16& l_acc,
                    f32x16& o0, f32x16& o1,
                    const bf16x8 v00, const bf16x8 v01,
                    const bf16x8 v10, const bf16x8 v11) {
        {
            // max of 16 via nested triples (fuses to v_max3_f32)
            const float t0 = fmaxf(fmaxf(s[0],  s[1]),  s[2]);
            const float t1 = fmaxf(fmaxf(s[3],  s[4]),  s[5]);
            const float t2 = fmaxf(fmaxf(s[6],  s[7]),  s[8]);
            const float t3 = fmaxf(fmaxf(s[9],  s[10]), s[11]);
            const float t4 = fmaxf(fmaxf(s[12], s[13]), s[14]);
            const float u0 = fmaxf(fmaxf(t0, t1), t2);
            const float u1 = fmaxf(fmaxf(t3, t4), s[15]);
            float tm = fmaxf(u0, u1);
            tm = fmaxf(tm, __shfl_xor(tm, 32));
            if (__any(tm > m_run + 8.f)) {
                const float nm = fmaxf(m_run, tm);
                const float sc = __builtin_amdgcn_exp2f(m_run - nm);
                m_run = nm;
                l_acc[0] *= sc;
                #pragma unroll
                for (int r = 0; r < 16; ++r) { o0[r] *= sc; o1[r] *= sc; }
            }
        }
        #pragma unroll
        for (int r = 0; r < 16; ++r) s[r] = __builtin_amdgcn_exp2f(s[r] - m_run);

        // pack P -> bf16 B-frags; half-wave exchange via permlane32_swap
        unsigned w0 = pk_bf16(s[0],  s[1]),  w1 = pk_bf16(s[2],  s[3]);
        unsigned w2 = pk_bf16(s[4],  s[5]),  w3 = pk_bf16(s[6],  s[7]);
        unsigned w4 = pk_bf16(s[8],  s[9]),  w5 = pk_bf16(s[10], s[11]);
        unsigned w6 = pk_bf16(s[12], s[13]), w7 = pk_bf16(s[14], s[15]);
        asm("v_permlane32_swap_b32 %0, %1" : "+v"(w0), "+v"(w2));
        asm("v_permlane32_swap_b32 %0, %1" : "+v"(w1), "+v"(w3));
        asm("v_permlane32_swap_b32 %0, %1" : "+v"(w4), "+v"(w6));
        asm("v_permlane32_swap_b32 %0, %1" : "+v"(w5), "+v"(w7));
        const bf16x8 pf0 = frag4(w0, w1, w2, w3);
        const bf16x8 pf1 = frag4(w4, w5, w6, w7);

        // l row-sum + O update on the matrix pipe
        l_acc = MFMA32(vones, pf0, l_acc);
        l_acc = MFMA32(vones, pf1, l_acc);
        o0 = MFMA32(v00, pf0, o0);
        o0 = MFMA32(v01, pf1, o0);
        o1 = MFMA32(v10, pf0, o1);
        o1 = MFMA32(v11, pf1, o1);
    };

    STAGE(0, kv0);
    asm volatile("s_waitcnt vmcnt(0)" ::: "memory");
    __builtin_amdgcn_s_barrier();

    for (int tt = 0; tt < NT; ++tt) {
        const int cur = tt & 1;
        if (tt < NT - 1) STAGE(cur ^ 1, kv0 + (tt + 1) * 64);

        #pragma unroll
        for (int s = 0; s < 2; ++s) {
            bf16x8 kf[4];
            #pragma unroll
            for (int ks = 0; ks < 4; ++ks)
                kf[ks] = *(const bf16x8*)&Ks[cur][(s * 32 + lq) * 64 +
                                                  (((ks * 2 + hi) ^ (lq & 7)) * 8)];
            f32x16 s0 = {}, s1 = {};
            #pragma unroll
            for (int ks = 0; ks < 4; ++ks) {
                s0 = MFMA32(kf[ks], qfA[ks], s0);
                s1 = MFMA32(kf[ks], qfB[ks], s1);
            }
            const int K0 = s * 4 + hi;
            const int K1 = s * 4 + 2 + hi;
            const bf16x8 v00 = *(const bf16x8*)&Vs[cur][lq * 64 + ((K0 ^ (lq & 7)) * 8)];
            const bf16x8 v10 = *(const bf16x8*)&Vs[cur][(32 + lq) * 64 + ((K0 ^ (lq & 7)) * 8)];
            const bf16x8 v01 = *(const bf16x8*)&Vs[cur][lq * 64 + ((K1 ^ (lq & 7)) * 8)];
            const bf16x8 v11 = *(const bf16x8*)&Vs[cur][(32 + lq) * 64 + ((K1 ^ (lq & 7)) * 8)];

            SMPV(s0, mA, laccA, oaA0, oaA1, v00, v01, v10, v11);
            SMPV(s1, mB, laccB, oaB0, oaB1, v00, v01, v10, v11);
        }

        asm volatile("s_waitcnt vmcnt(0) lgkmcnt(0)" ::: "memory");
        __builtin_amdgcn_s_barrier();
    }

    auto EPI = [&](const f32x16& o_0, const f32x16& o_1, float l_run, int nq) {
        const float inv = 1.f / l_run;
        #pragma unroll
        for (int ct = 0; ct < 2; ++ct) {
            f32x16 o = ct ? o_1 : o_0;
            #pragma unroll
            for (int r = 0; r < 16; ++r) o[r] *= inv;
            unsigned w0 = pk_bf16(o[0],  o[1]),  w1 = pk_bf16(o[2],  o[3]);
            unsigned w2 = pk_bf16(o[4],  o[5]),  w3 = pk_bf16(o[6],  o[7]);
            unsigned w4 = pk_bf16(o[8],  o[9]),  w5 = pk_bf16(o[10], o[11]);
            unsigned w6 = pk_bf16(o[12], o[13]), w7 = pk_bf16(o[14], o[15]);
            asm("v_permlane32_swap_b32 %0, %1" : "+v"(w0), "+v"(w2));
            asm("v_permlane32_swap_b32 %0, %1" : "+v"(w1), "+v"(w3));
            asm("v_permlane32_swap_b32 %0, %1" : "+v"(w4), "+v"(w6));
            asm("v_permlane32_swap_b32 %0, %1" : "+v"(w5), "+v"(w7));
            bf16x8 ob0 = frag4(w0, w1, w2, w3);
            bf16x8 ob1 = frag4(w4, w5, w6, w7);
            bf16_t* op = Opart + (((size_t)(b * NSPLIT + split)) * 4096 + nq) * 64 + ct * 32;
            *(bf16x8*)(op + hi * 8)      = ob0;
            *(bf16x8*)(op + 16 + hi * 8) = ob1;
        }
    };
    EPI(oaA0, oaA1, laccA[0], qA);
    EPI(oaB0, oaB1, laccB[0], qB);

    if (hi == 0) {
        float2 va; va.x = mA; va.y = laccA[0];
        *(float2*)&ml[(((size_t)(b * NSPLIT + split)) * 4096 + qA) * 2] = va;
        float2 vbv; vbv.x = mB; vbv.y = laccB[0];
        *(float2*)&ml[(((size_t)(b * NSPLIT + split)) * 4096 + qB) * 2] = vbv;
    }
}

// ---------------------------------------------------------------------------
// Kernel 3 (v1, round-12/14 measured-best): combine partials + out-proj +
// bias + skip. Grid: (64 q-tiles of 64, 8 batches), 512 threads (8 waves).
// ---------------------------------------------------------------------------
template <int NSPLIT>
__global__ __launch_bounds__(512) void combine_kernel(
    const bf16_t* __restrict__ Opart, const float* __restrict__ ml,
    const float* __restrict__ x, const float* __restrict__ w_out,
    const float* __restrict__ b_out, float* __restrict__ y)
{
    const int b    = blockIdx.y;
    const int t    = threadIdx.x;
    const int lane = t & 63;
    const int wave = t >> 6;          // 0..7
    const int lq   = lane & 31;
    const int hi   = lane >> 5;
    const int group = wave >> 2;      // 0..1
    const int nq   = blockIdx.x * 64 + group * 32 + lq;

    float coef[NSPLIT];
    {
        float m_s[NSPLIT], l_s[NSPLIT];
        #pragma unroll
        for (int s = 0; s < NSPLIT; ++s) {
            float2 v = *(const float2*)&ml[(((size_t)(b * NSPLIT + s)) * 4096 + nq) * 2];
            m_s[s] = v.x; l_s[s] = v.y;
        }
        float M = m_s[0];
        #pragma unroll
        for (int s = 1; s < NSPLIT; ++s) M = fmaxf(M, m_s[s]);
        float L = 0.f;
        #pragma unroll
        for (int s = 0; s < NSPLIT; ++s) {
            coef[s] = __builtin_amdgcn_exp2f(m_s[s] - M) * l_s[s];
            L += coef[s];
        }
        const float invL = 1.f / L;
        #pragma unroll
        for (int s = 0; s < NSPLIT; ++s) coef[s] *= invL;
    }

    bf16x8 obf[4];
    #pragma unroll
    for (int ks = 0; ks < 4; ++ks) {
        float a8[8] = {};
        #pragma unroll
        for (int s = 0; s < NSPLIT; ++s) {
            bf16x8 o = *(const bf16x8*)&Opart[
                (((size_t)(b * NSPLIT + s)) * 4096 + nq) * 64 + ks * 16 + hi * 8];
            #pragma unroll
            for (int j = 0; j < 8; ++j) a8[j] += coef[s] * (float)o[j];
        }
        obf[ks] = frag4(pk_bf16(a8[0], a8[1]), pk_bf16(a8[2], a8[3]),
                        pk_bf16(a8[4], a8[5]), pk_bf16(a8[6], a8[7]));
    }

    #pragma unroll 1
    for (int i = 0; i < 4; ++i) {
        const int mt = (wave & 3) * 4 + i;
        f32x16 acc = {};
        #pragma unroll
        for (int ks = 0; ks < 4; ++ks) {
            const float* wp = w_out + (size_t)(mt * 32 + lq) * 64 + ks * 16 + hi * 8;
            f32x4 a0 = *(const f32x4*)wp;
            f32x4 a1 = *(const f32x4*)(wp + 4);
            bf16x8 af = frag4(pk_bf16(a0[0], a0[1]), pk_bf16(a0[2], a0[3]),
                              pk_bf16(a1[0], a1[1]), pk_bf16(a1[2], a1[3]));
            acc = MFMA32(af, obf[ks], acc);
        }
        #pragma unroll
        for (int r = 0; r < 16; ++r) {
            const int m = mt * 32 + (r & 3) + 8 * (r >> 2) + 4 * hi;
            const size_t idx = ((size_t)b * 512 + m) * 4096 + nq;
            y[idx] = acc[r] + b_out[m] + x[idx];
        }
    }
}

// ---------------------------------------------------------------------------
extern "C" void kernel_launch(void* const* d_in, const int* in_sizes, int n_in,
                              void* d_out, int out_size, void* d_ws, size_t ws_size,
                              hipStream_t stream)
{
    const float* x     = (const float*)d_in[0];
    const float* w_in  = (const float*)d_in[1];
    const float* b_in  = (const float*)d_in[2];
    const float* w_out = (const float*)d_in[3];
    const float* b_out = (const float*)d_in[4];
    float* y = (float*)d_out;

    char* ws = (char*)d_ws;
    bf16_t* q_r   = (bf16_t*)(ws);                       // 4 MiB
    bf16_t* k_r   = (bf16_t*)(ws + 4194304);             // 4 MiB
    bf16_t* v_t   = (bf16_t*)(ws + 8388608);             // 4 MiB
    bf16_t* Opart = (bf16_t*)(ws + 12582912);            // 16 MiB (NSPLIT=4)
    float*  ml    = (float*)(ws + 12582912 + 16777216);  // 1 MiB
    bf16_t* wb    = (bf16_t*)(ws + 12582912 + 16777216 + 2097152);  // 192 KiB

    wconv_kernel<<<dim3(96), 256, 0, stream>>>(w_in, wb);
    qkv_kernel<<<dim3(64, 8), 256, 0, stream>>>(x, wb, b_in, q_r, k_r, v_t);
    attn_partial_kernel<4><<<dim3(16, 8, 4), 256, 0, stream>>>(q_r, k_r, v_t, Opart, ml);
    combine_kernel<4><<<dim3(64, 8), 512, 0, stream>>>(Opart, ml, x, w_out, b_out, y);
}